// Round 2
// baseline (1273.518 us; speedup 1.0000x reference)
//
#include <hip/hip_runtime.h>

// SelectionGNN clique+line. I/O: float32 (per reference). Internals: bf16 MFMA
// with fp32 accumulate; intermediates stored f32 (only inputs get rounded).
// B=8, N=4096, E=1, K=3 taps, F=[16,32,16], MLP 65536->64->1.

#define NN 4096
#define BB 8

typedef unsigned short u16;
typedef unsigned int   u32;

typedef __attribute__((ext_vector_type(8))) short bf16x8;  // 8 bf16 = 4 VGPRs
typedef __attribute__((ext_vector_type(4))) float f32x4;

__device__ __forceinline__ u16 f2bf(float f) {
    union { float f; u32 i; } c; c.f = f;
    u32 i = c.i;
    u32 r = (i + 0x7FFFu + ((i >> 16) & 1u)) >> 16;  // RTNE
    return (u16)r;
}

// ---------------------------------------------------------------------------
// f32 -> bf16 conversion (for S matrices), grid-stride, float4 -> ushort4.
// n must be a multiple of 4 (NN*NN is).
// ---------------------------------------------------------------------------
__global__ __launch_bounds__(256) void cvt_f32_bf16(const float* __restrict__ in,
                                                    u16* __restrict__ out, int n)
{
    int i = (blockIdx.x * 256 + threadIdx.x) * 4;
    const int stride = gridDim.x * 256 * 4;
    for (; i < n; i += stride) {
        float4 v = *(const float4*)(in + i);
        ushort4 o;
        o.x = f2bf(v.x); o.y = f2bf(v.y); o.z = f2bf(v.z); o.w = f2bf(v.w);
        *(ushort4*)(out + i) = o;
    }
}

// ---------------------------------------------------------------------------
// Diffusion: Out[r,n] = sum_m Z[r,m] * S[n,m]   (C = Z * S^T), fp32 out.
// Z: [M,4096] f32. S: [4096,4096], either bf16 (pre-converted) or f32
// (fallback, converted during staging). Tile 64x64, BK=64, 4 waves 2x2,
// each wave 32x32 via 2x2 mfma_f32_16x16x32_bf16.
// grid: (NN/64, M/64)
// ---------------------------------------------------------------------------
template <typename TB>
__global__ __launch_bounds__(256) void diffuse(const float* __restrict__ Z,
                                               const TB* __restrict__ S,
                                               float* __restrict__ Out)
{
    // +8 pad (144 B row stride): 2-way bank aliasing on ds_read_b128 is free.
    __shared__ u16 As[64][72];
    __shared__ u16 Bs[64][72];

    const int mBase = blockIdx.y * 64;
    const int nBase = blockIdx.x * 64;
    const int tid   = threadIdx.x;

    // f32 staging coords: 16 threads x float4 cover one row of 64
    const int ar = tid >> 4;          // 0..15
    const int ac = (tid & 15) * 4;    // 0,4,..,60
    // bf16 staging coords: 8 threads x 8 bf16 cover one row of 64
    const int br = tid >> 3;          // 0..31
    const int bc = (tid & 7) * 8;     // 0,8,..,56

    // compute coords
    const int lane = tid & 63;
    const int wv   = tid >> 6;
    const int wm   = wv >> 1;
    const int wn   = wv & 1;
    const int quad = lane >> 4;
    const int l16  = lane & 15;

    f32x4 acc[2][2];
#pragma unroll
    for (int i = 0; i < 2; ++i)
#pragma unroll
        for (int j = 0; j < 2; ++j) acc[i][j] = (f32x4){0.f, 0.f, 0.f, 0.f};

    for (int k0 = 0; k0 < NN; k0 += 64) {
        // A tile: f32 -> bf16
#pragma unroll
        for (int p = 0; p < 4; ++p) {
            const int r = ar + p * 16;
            float4 v = *(const float4*)(Z + (size_t)(mBase + r) * NN + k0 + ac);
            ushort4 o;
            o.x = f2bf(v.x); o.y = f2bf(v.y); o.z = f2bf(v.z); o.w = f2bf(v.w);
            *(ushort4*)&As[r][ac] = o;
        }
        // B tile
        if constexpr (sizeof(TB) == 2) {
#pragma unroll
            for (int p = 0; p < 2; ++p) {
                const int r = br + p * 32;
                *(uint4*)&Bs[r][bc] =
                    *(const uint4*)((const u16*)S + (size_t)(nBase + r) * NN + k0 + bc);
            }
        } else {
#pragma unroll
            for (int p = 0; p < 4; ++p) {
                const int r = ar + p * 16;
                float4 v = *(const float4*)((const float*)S + (size_t)(nBase + r) * NN + k0 + ac);
                ushort4 o;
                o.x = f2bf(v.x); o.y = f2bf(v.y); o.z = f2bf(v.z); o.w = f2bf(v.w);
                *(ushort4*)&Bs[r][ac] = o;
            }
        }
        __syncthreads();

#pragma unroll
        for (int s = 0; s < 2; ++s) {
            const int kc = s * 32 + quad * 8;
            bf16x8 af[2], bf[2];
            af[0] = *(const bf16x8*)&As[wm * 32 + l16][kc];
            af[1] = *(const bf16x8*)&As[wm * 32 + 16 + l16][kc];
            bf[0] = *(const bf16x8*)&Bs[wn * 32 + l16][kc];
            bf[1] = *(const bf16x8*)&Bs[wn * 32 + 16 + l16][kc];
#pragma unroll
            for (int mi = 0; mi < 2; ++mi)
#pragma unroll
                for (int ni = 0; ni < 2; ++ni)
                    acc[mi][ni] = __builtin_amdgcn_mfma_f32_16x16x32_bf16(
                        af[mi], bf[ni], acc[mi][ni], 0, 0, 0);
        }
        __syncthreads();
    }

    // D mapping: col = lane&15, row = quad*4 + reg
#pragma unroll
    for (int mi = 0; mi < 2; ++mi)
#pragma unroll
        for (int ni = 0; ni < 2; ++ni) {
            const int row0 = mBase + wm * 32 + mi * 16 + quad * 4;
            const int col  = nBase + wn * 32 + ni * 16 + l16;
#pragma unroll
            for (int i = 0; i < 4; ++i)
                Out[(size_t)(row0 + i) * NN + col] = acc[mi][ni][i];
        }
}

// ---------------------------------------------------------------------------
// Tap combine + ReLU (all f32):
// out[b,g,n] = relu( bias[g] + sum_{k<3} sum_{f<FIN} W[g,k,f] * z_k[b,f,n] )
// grid: BB*NN/256, 256 threads, one (b,n) per thread.
// ---------------------------------------------------------------------------
template <int FIN, int FOUT>
__global__ __launch_bounds__(256) void combine_relu(
    const float* __restrict__ z0, const float* __restrict__ z1,
    const float* __restrict__ z2, const float* __restrict__ W,
    const float* __restrict__ bias, float* __restrict__ out)
{
    __shared__ float hs[FOUT * 3 * FIN];
    __shared__ float bs[FOUT];
    for (int i = threadIdx.x; i < FOUT * 3 * FIN; i += 256) hs[i] = W[i];
    if (threadIdx.x < FOUT) bs[threadIdx.x] = bias[threadIdx.x];
    __syncthreads();

    const int nb = NN / 256;                 // 16
    const int b  = blockIdx.x / nb;
    const int n  = (blockIdx.x % nb) * 256 + threadIdx.x;

    float zv[3][FIN];
    const float* zp0 = z0 + (size_t)b * FIN * NN + n;
    const float* zp1 = z1 + (size_t)b * FIN * NN + n;
    const float* zp2 = z2 + (size_t)b * FIN * NN + n;
#pragma unroll
    for (int f = 0; f < FIN; ++f) {
        zv[0][f] = zp0[(size_t)f * NN];
        zv[1][f] = zp1[(size_t)f * NN];
        zv[2][f] = zp2[(size_t)f * NN];
    }

    float* op = out + (size_t)b * FOUT * NN + n;
    for (int g = 0; g < FOUT; ++g) {
        float acc = bs[g];
#pragma unroll
        for (int k = 0; k < 3; ++k)
#pragma unroll
            for (int f = 0; f < FIN; ++f)
                acc = fmaf(hs[(g * 3 + k) * FIN + f], zv[k][f], acc);
        op[(size_t)g * NN] = fmaxf(acc, 0.f);
    }
}

// ---------------------------------------------------------------------------
// MLP layer 1: h1[b,j] = relu( bm1[j] + sum_i y[b,i]*Wm1[j,i] ), D=65536.
// grid: 64 blocks (one j each), 256 threads.
// ---------------------------------------------------------------------------
__global__ __launch_bounds__(256) void mlp1(const float* __restrict__ y,
                                            const float* __restrict__ Wm1,
                                            const float* __restrict__ bm1,
                                            float* __restrict__ h1)
{
    const int j = blockIdx.x;
    const int D = 16 * NN;  // 65536
    float acc[BB];
#pragma unroll
    for (int b = 0; b < BB; ++b) acc[b] = 0.f;

    const float* wrow = Wm1 + (size_t)j * D;
    for (int idx = threadIdx.x * 4; idx < D; idx += 256 * 4) {
        float4 w = *(const float4*)(wrow + idx);
#pragma unroll
        for (int b = 0; b < BB; ++b) {
            float4 yv = *(const float4*)(y + (size_t)b * D + idx);
            acc[b] = fmaf(w.x, yv.x, acc[b]);
            acc[b] = fmaf(w.y, yv.y, acc[b]);
            acc[b] = fmaf(w.z, yv.z, acc[b]);
            acc[b] = fmaf(w.w, yv.w, acc[b]);
        }
    }

    __shared__ float red[BB][4];
    const int lane = threadIdx.x & 63;
    const int w    = threadIdx.x >> 6;
#pragma unroll
    for (int b = 0; b < BB; ++b) {
        float v = acc[b];
        for (int off = 32; off > 0; off >>= 1) v += __shfl_down(v, off, 64);
        if (lane == 0) red[b][w] = v;
    }
    __syncthreads();
    if (threadIdx.x < BB) {
        const int b = threadIdx.x;
        float v = red[b][0] + red[b][1] + red[b][2] + red[b][3] + bm1[j];
        h1[b * 64 + j] = fmaxf(v, 0.f);
    }
}

// ---------------------------------------------------------------------------
// MLP layer 2: out[b] = bm2 + sum_{j<64} h1[b,j]*Wm2[j].  1 block, 64 lanes.
// ---------------------------------------------------------------------------
__global__ void mlp2(const float* __restrict__ h1, const float* __restrict__ Wm2,
                     const float* __restrict__ bm2, float* __restrict__ out)
{
    const int lane = threadIdx.x;  // 0..63
    const float w    = Wm2[lane];
    const float bias = bm2[0];
    for (int b = 0; b < BB; ++b) {
        float v = h1[b * 64 + lane] * w;
        for (int off = 32; off > 0; off >>= 1) v += __shfl_down(v, off, 64);
        if (lane == 0) out[b] = v + bias;
    }
}

// ---------------------------------------------------------------------------
extern "C" void kernel_launch(void* const* d_in, const int* in_sizes, int n_in,
                              void* d_out, int out_size, void* d_ws, size_t ws_size,
                              hipStream_t stream)
{
    const float* x   = (const float*)d_in[0];   // [8,16,4096]
    const float* Sc  = (const float*)d_in[1];   // [1,4096,4096]
    const float* Sl  = (const float*)d_in[2];   // [1,4096,4096]
    const float* Wc1 = (const float*)d_in[3];   // [32,1,3,16]
    const float* bc1 = (const float*)d_in[4];
    const float* Wc2 = (const float*)d_in[5];   // [16,1,3,32]
    const float* bc2 = (const float*)d_in[6];
    const float* Wl1 = (const float*)d_in[7];
    const float* bl1 = (const float*)d_in[8];
    const float* Wl2 = (const float*)d_in[9];
    const float* bl2 = (const float*)d_in[10];
    const float* Wm1 = (const float*)d_in[11];  // [64,65536]
    const float* bm1 = (const float*)d_in[12];
    const float* Wm2 = (const float*)d_in[13];  // [1,64]
    const float* bm2 = (const float*)d_in[14];
    float* out = (float*)d_out;                 // [8,1] f32

    char* ws = (char*)d_ws;
    float* z1 = (float*)(ws);                    // 4 MB ([8,32,4096] f32 max)
    float* z2 = (float*)(ws + (4u << 20));       // 4 MB
    float* yA = (float*)(ws + (8u << 20));       // 4 MB
    float* yB = (float*)(ws + (12u << 20));      // 4 MB
    float* h1 = (float*)(ws + (16u << 20));      // 2 KB
    u16* Scb  = (u16*)(ws + (17u << 20));        // 32 MB
    u16* Slb  = Scb + (size_t)NN * NN;           // 32 MB
    const size_t needed = (17u << 20) + 2 * (size_t)NN * NN * sizeof(u16);
    const bool bigws = ws_size >= needed;

    const dim3 blk(256);
    const dim3 gridCmb(BB * NN / 256);           // 128
    const dim3 g2(NN / 64, 2), g4(NN / 64, 4);

    if (bigws) {
        cvt_f32_bf16<<<1024, blk, 0, stream>>>(Sc, Scb, NN * NN);
        cvt_f32_bf16<<<1024, blk, 0, stream>>>(Sl, Slb, NN * NN);
        // Layer 1: clique, Fin=16 (M=128) -> Fout=32
        diffuse<u16><<<g2, blk, 0, stream>>>(x, Scb, z1);
        diffuse<u16><<<g2, blk, 0, stream>>>(z1, Scb, z2);
        combine_relu<16, 32><<<gridCmb, blk, 0, stream>>>(x, z1, z2, Wc1, bc1, yA);
        // Layer 2: clique, Fin=32 (M=256) -> Fout=16
        diffuse<u16><<<g4, blk, 0, stream>>>(yA, Scb, z1);
        diffuse<u16><<<g4, blk, 0, stream>>>(z1, Scb, z2);
        combine_relu<32, 16><<<gridCmb, blk, 0, stream>>>(yA, z1, z2, Wc2, bc2, yB);
        // Layer 3: line, Fin=16 (M=128) -> Fout=32
        diffuse<u16><<<g2, blk, 0, stream>>>(yB, Slb, z1);
        diffuse<u16><<<g2, blk, 0, stream>>>(z1, Slb, z2);
        combine_relu<16, 32><<<gridCmb, blk, 0, stream>>>(yB, z1, z2, Wl1, bl1, yA);
        // Layer 4: line, Fin=32 (M=256) -> Fout=16
        diffuse<u16><<<g4, blk, 0, stream>>>(yA, Slb, z1);
        diffuse<u16><<<g4, blk, 0, stream>>>(z1, Slb, z2);
        combine_relu<32, 16><<<gridCmb, blk, 0, stream>>>(yA, z1, z2, Wl2, bl2, yB);
    } else {
        // Fallback: stage S f32 tiles directly (converted in-kernel).
        diffuse<float><<<g2, blk, 0, stream>>>(x, Sc, z1);
        diffuse<float><<<g2, blk, 0, stream>>>(z1, Sc, z2);
        combine_relu<16, 32><<<gridCmb, blk, 0, stream>>>(x, z1, z2, Wc1, bc1, yA);
        diffuse<float><<<g4, blk, 0, stream>>>(yA, Sc, z1);
        diffuse<float><<<g4, blk, 0, stream>>>(z1, Sc, z2);
        combine_relu<32, 16><<<gridCmb, blk, 0, stream>>>(yA, z1, z2, Wc2, bc2, yB);
        diffuse<float><<<g2, blk, 0, stream>>>(yB, Sl, z1);
        diffuse<float><<<g2, blk, 0, stream>>>(z1, Sl, z2);
        combine_relu<16, 32><<<gridCmb, blk, 0, stream>>>(yB, z1, z2, Wl1, bl1, yA);
        diffuse<float><<<g4, blk, 0, stream>>>(yA, Sl, z1);
        diffuse<float><<<g4, blk, 0, stream>>>(z1, Sl, z2);
        combine_relu<32, 16><<<gridCmb, blk, 0, stream>>>(yA, z1, z2, Wl2, bl2, yB);
    }
    mlp1<<<64, blk, 0, stream>>>(yB, Wm1, bm1, h1);
    mlp2<<<1, 64, 0, stream>>>(h1, Wm2, bm2, out);
}

// Round 3
// 611.617 us; speedup vs baseline: 2.0822x; 2.0822x over previous
//
#include <hip/hip_runtime.h>

// SelectionGNN clique+line. I/O: float32 (per reference). Internals: bf16 MFMA
// with fp32 accumulate; intermediates stored f32 (only inputs get rounded).
// B=8, N=4096, E=1, K=3 taps, F=[16,32,16], MLP 65536->64->1.
// R2: split-K diffuse (gridDim.z splits, f32 atomic accumulate) to fix the
// 5.9% occupancy / latency-bound 155us-per-diffuse problem seen in R1.

#define NN 4096
#define BB 8

typedef unsigned short u16;
typedef unsigned int   u32;

typedef __attribute__((ext_vector_type(8))) short bf16x8;  // 8 bf16 = 4 VGPRs
typedef __attribute__((ext_vector_type(4))) float f32x4;

__device__ __forceinline__ u16 f2bf(float f) {
    union { float f; u32 i; } c; c.f = f;
    u32 i = c.i;
    u32 r = (i + 0x7FFFu + ((i >> 16) & 1u)) >> 16;  // RTNE
    return (u16)r;
}

// ---------------------------------------------------------------------------
// f32 -> bf16 conversion (for S matrices), grid-stride, float4 -> ushort4.
// ---------------------------------------------------------------------------
__global__ __launch_bounds__(256) void cvt_f32_bf16(const float* __restrict__ in,
                                                    u16* __restrict__ out, int n)
{
    int i = (blockIdx.x * 256 + threadIdx.x) * 4;
    const int stride = gridDim.x * 256 * 4;
    for (; i < n; i += stride) {
        float4 v = *(const float4*)(in + i);
        ushort4 o;
        o.x = f2bf(v.x); o.y = f2bf(v.y); o.z = f2bf(v.z); o.w = f2bf(v.w);
        *(ushort4*)(out + i) = o;
    }
}

// ---------------------------------------------------------------------------
// Split-K diffusion: Out[r,n] += sum_{m in K-slice} Z[r,m] * S[n,m]
// (C = Z * S^T, fp32 atomic accumulate; Out must be pre-zeroed).
// Z: [M,4096] f32. S: [4096,4096] bf16 (or f32 fallback, converted in-stage).
// Tile 64x64, BK=64, 4 waves 2x2, wave = 32x32 via 2x2 mfma_16x16x32_bf16.
// grid: (NN/64, M/64, KS); block's K-slice = NN/KS elements.
// ---------------------------------------------------------------------------
template <typename TB>
__global__ __launch_bounds__(256) void diffuse(const float* __restrict__ Z,
                                               const TB* __restrict__ S,
                                               float* __restrict__ Out)
{
    // +8 pad (144 B row stride): 2-way bank aliasing on ds_read_b128 is free.
    __shared__ u16 As[64][72];
    __shared__ u16 Bs[64][72];

    const int mBase = blockIdx.y * 64;
    const int nBase = blockIdx.x * 64;
    const int tid   = threadIdx.x;

    const int kSlice = NN / gridDim.z;
    const int kStart = blockIdx.z * kSlice;
    const int kEnd   = kStart + kSlice;

    // f32 staging coords: 16 threads x float4 cover one row of 64
    const int ar = tid >> 4;          // 0..15
    const int ac = (tid & 15) * 4;    // 0,4,..,60
    // bf16 staging coords: 8 threads x 8 bf16 cover one row of 64
    const int br = tid >> 3;          // 0..31
    const int bc = (tid & 7) * 8;     // 0,8,..,56

    // compute coords
    const int lane = tid & 63;
    const int wv   = tid >> 6;
    const int wm   = wv >> 1;
    const int wn   = wv & 1;
    const int quad = lane >> 4;
    const int l16  = lane & 15;

    f32x4 acc[2][2];
#pragma unroll
    for (int i = 0; i < 2; ++i)
#pragma unroll
        for (int j = 0; j < 2; ++j) acc[i][j] = (f32x4){0.f, 0.f, 0.f, 0.f};

    for (int k0 = kStart; k0 < kEnd; k0 += 64) {
        // A tile: f32 -> bf16
#pragma unroll
        for (int p = 0; p < 4; ++p) {
            const int r = ar + p * 16;
            float4 v = *(const float4*)(Z + (size_t)(mBase + r) * NN + k0 + ac);
            ushort4 o;
            o.x = f2bf(v.x); o.y = f2bf(v.y); o.z = f2bf(v.z); o.w = f2bf(v.w);
            *(ushort4*)&As[r][ac] = o;
        }
        // B tile
        if constexpr (sizeof(TB) == 2) {
#pragma unroll
            for (int p = 0; p < 2; ++p) {
                const int r = br + p * 32;
                *(uint4*)&Bs[r][bc] =
                    *(const uint4*)((const u16*)S + (size_t)(nBase + r) * NN + k0 + bc);
            }
        } else {
#pragma unroll
            for (int p = 0; p < 4; ++p) {
                const int r = ar + p * 16;
                float4 v = *(const float4*)((const float*)S + (size_t)(nBase + r) * NN + k0 + ac);
                ushort4 o;
                o.x = f2bf(v.x); o.y = f2bf(v.y); o.z = f2bf(v.z); o.w = f2bf(v.w);
                *(ushort4*)&Bs[r][ac] = o;
            }
        }
        __syncthreads();

#pragma unroll
        for (int s = 0; s < 2; ++s) {
            const int kc = s * 32 + quad * 8;
            bf16x8 af[2], bf[2];
            af[0] = *(const bf16x8*)&As[wm * 32 + l16][kc];
            af[1] = *(const bf16x8*)&As[wm * 32 + 16 + l16][kc];
            bf[0] = *(const bf16x8*)&Bs[wn * 32 + l16][kc];
            bf[1] = *(const bf16x8*)&Bs[wn * 32 + 16 + l16][kc];
#pragma unroll
            for (int mi = 0; mi < 2; ++mi)
#pragma unroll
                for (int ni = 0; ni < 2; ++ni)
                    acc[mi][ni] = __builtin_amdgcn_mfma_f32_16x16x32_bf16(
                        af[mi], bf[ni], acc[mi][ni], 0, 0, 0);
        }
        __syncthreads();
    }

    // D mapping: col = lane&15, row = quad*4 + reg.  Atomic accumulate.
#pragma unroll
    for (int mi = 0; mi < 2; ++mi)
#pragma unroll
        for (int ni = 0; ni < 2; ++ni) {
            const int row0 = mBase + wm * 32 + mi * 16 + quad * 4;
            const int col  = nBase + wn * 32 + ni * 16 + l16;
#pragma unroll
            for (int i = 0; i < 4; ++i)
                atomicAdd(&Out[(size_t)(row0 + i) * NN + col], acc[mi][ni][i]);
        }
}

// ---------------------------------------------------------------------------
// Tap combine + ReLU (all f32):
// out[b,g,n] = relu( bias[g] + sum_{k<3} sum_{f<FIN} W[g,k,f] * z_k[b,f,n] )
// grid: BB*NN/256, 256 threads, one (b,n) per thread.
// ---------------------------------------------------------------------------
template <int FIN, int FOUT>
__global__ __launch_bounds__(256) void combine_relu(
    const float* __restrict__ z0, const float* __restrict__ z1,
    const float* __restrict__ z2, const float* __restrict__ W,
    const float* __restrict__ bias, float* __restrict__ out)
{
    __shared__ float hs[FOUT * 3 * FIN];
    __shared__ float bs[FOUT];
    for (int i = threadIdx.x; i < FOUT * 3 * FIN; i += 256) hs[i] = W[i];
    if (threadIdx.x < FOUT) bs[threadIdx.x] = bias[threadIdx.x];
    __syncthreads();

    const int nb = NN / 256;                 // 16
    const int b  = blockIdx.x / nb;
    const int n  = (blockIdx.x % nb) * 256 + threadIdx.x;

    float zv[3][FIN];
    const float* zp0 = z0 + (size_t)b * FIN * NN + n;
    const float* zp1 = z1 + (size_t)b * FIN * NN + n;
    const float* zp2 = z2 + (size_t)b * FIN * NN + n;
#pragma unroll
    for (int f = 0; f < FIN; ++f) {
        zv[0][f] = zp0[(size_t)f * NN];
        zv[1][f] = zp1[(size_t)f * NN];
        zv[2][f] = zp2[(size_t)f * NN];
    }

    float* op = out + (size_t)b * FOUT * NN + n;
    for (int g = 0; g < FOUT; ++g) {
        float acc = bs[g];
#pragma unroll
        for (int k = 0; k < 3; ++k)
#pragma unroll
            for (int f = 0; f < FIN; ++f)
                acc = fmaf(hs[(g * 3 + k) * FIN + f], zv[k][f], acc);
        op[(size_t)g * NN] = fmaxf(acc, 0.f);
    }
}

// ---------------------------------------------------------------------------
// MLP layer 1: h1[b,j] = relu( bm1[j] + sum_i y[b,i]*Wm1[j,i] ), D=65536.
// grid: 64 blocks (one j each), 256 threads.
// ---------------------------------------------------------------------------
__global__ __launch_bounds__(256) void mlp1(const float* __restrict__ y,
                                            const float* __restrict__ Wm1,
                                            const float* __restrict__ bm1,
                                            float* __restrict__ h1)
{
    const int j = blockIdx.x;
    const int D = 16 * NN;  // 65536
    float acc[BB];
#pragma unroll
    for (int b = 0; b < BB; ++b) acc[b] = 0.f;

    const float* wrow = Wm1 + (size_t)j * D;
    for (int idx = threadIdx.x * 4; idx < D; idx += 256 * 4) {
        float4 w = *(const float4*)(wrow + idx);
#pragma unroll
        for (int b = 0; b < BB; ++b) {
            float4 yv = *(const float4*)(y + (size_t)b * D + idx);
            acc[b] = fmaf(w.x, yv.x, acc[b]);
            acc[b] = fmaf(w.y, yv.y, acc[b]);
            acc[b] = fmaf(w.z, yv.z, acc[b]);
            acc[b] = fmaf(w.w, yv.w, acc[b]);
        }
    }

    __shared__ float red[BB][4];
    const int lane = threadIdx.x & 63;
    const int w    = threadIdx.x >> 6;
#pragma unroll
    for (int b = 0; b < BB; ++b) {
        float v = acc[b];
        for (int off = 32; off > 0; off >>= 1) v += __shfl_down(v, off, 64);
        if (lane == 0) red[b][w] = v;
    }
    __syncthreads();
    if (threadIdx.x < BB) {
        const int b = threadIdx.x;
        float v = red[b][0] + red[b][1] + red[b][2] + red[b][3] + bm1[j];
        h1[b * 64 + j] = fmaxf(v, 0.f);
    }
}

// ---------------------------------------------------------------------------
// MLP layer 2: out[b] = bm2 + sum_{j<64} h1[b,j]*Wm2[j].  1 block, 64 lanes.
// ---------------------------------------------------------------------------
__global__ void mlp2(const float* __restrict__ h1, const float* __restrict__ Wm2,
                     const float* __restrict__ bm2, float* __restrict__ out)
{
    const int lane = threadIdx.x;  // 0..63
    const float w    = Wm2[lane];
    const float bias = bm2[0];
    for (int b = 0; b < BB; ++b) {
        float v = h1[b * 64 + lane] * w;
        for (int off = 32; off > 0; off >>= 1) v += __shfl_down(v, off, 64);
        if (lane == 0) out[b] = v + bias;
    }
}

// ---------------------------------------------------------------------------
extern "C" void kernel_launch(void* const* d_in, const int* in_sizes, int n_in,
                              void* d_out, int out_size, void* d_ws, size_t ws_size,
                              hipStream_t stream)
{
    const float* x   = (const float*)d_in[0];   // [8,16,4096]
    const float* Sc  = (const float*)d_in[1];   // [1,4096,4096]
    const float* Sl  = (const float*)d_in[2];   // [1,4096,4096]
    const float* Wc1 = (const float*)d_in[3];   // [32,1,3,16]
    const float* bc1 = (const float*)d_in[4];
    const float* Wc2 = (const float*)d_in[5];   // [16,1,3,32]
    const float* bc2 = (const float*)d_in[6];
    const float* Wl1 = (const float*)d_in[7];
    const float* bl1 = (const float*)d_in[8];
    const float* Wl2 = (const float*)d_in[9];
    const float* bl2 = (const float*)d_in[10];
    const float* Wm1 = (const float*)d_in[11];  // [64,65536]
    const float* bm1 = (const float*)d_in[12];
    const float* Wm2 = (const float*)d_in[13];  // [1,64]
    const float* bm2 = (const float*)d_in[14];
    float* out = (float*)d_out;                 // [8,1] f32

    char* ws = (char*)d_ws;
    float* z1 = (float*)(ws);                    // 4 MB ([8,32,4096] f32 max)
    float* z2 = (float*)(ws + (4u << 20));       // 4 MB
    float* yA = (float*)(ws + (8u << 20));       // 4 MB
    float* yB = (float*)(ws + (12u << 20));      // 4 MB
    float* h1 = (float*)(ws + (16u << 20));      // 2 KB
    u16* Scb  = (u16*)(ws + (17u << 20));        // 32 MB
    u16* Slb  = Scb + (size_t)NN * NN;           // 32 MB
    const size_t needed = (17u << 20) + 2 * (size_t)NN * NN * sizeof(u16);
    const bool bigws = ws_size >= needed;

    const dim3 blk(256);
    const dim3 gridCmb(BB * NN / 256);           // 128
    // split-K grids: always ~1024 blocks -> 4 blocks/CU, 16 waves/CU
    const dim3 g2(NN / 64, 2, 8);                // M=128, KS=8
    const dim3 g4(NN / 64, 4, 4);                // M=256, KS=4

    const size_t sz128 = (size_t)128 * NN * sizeof(float);  // 2 MB
    const size_t sz256 = (size_t)256 * NN * sizeof(float);  // 4 MB

#define ZERO(p, b) hipMemsetAsync((p), 0, (b), stream)

    if (bigws) {
        cvt_f32_bf16<<<1024, blk, 0, stream>>>(Sc, Scb, NN * NN);
        cvt_f32_bf16<<<1024, blk, 0, stream>>>(Sl, Slb, NN * NN);
        // Layer 1: clique, Fin=16 (M=128) -> Fout=32
        ZERO(z1, sz128); diffuse<u16><<<g2, blk, 0, stream>>>(x, Scb, z1);
        ZERO(z2, sz128); diffuse<u16><<<g2, blk, 0, stream>>>(z1, Scb, z2);
        combine_relu<16, 32><<<gridCmb, blk, 0, stream>>>(x, z1, z2, Wc1, bc1, yA);
        // Layer 2: clique, Fin=32 (M=256) -> Fout=16
        ZERO(z1, sz256); diffuse<u16><<<g4, blk, 0, stream>>>(yA, Scb, z1);
        ZERO(z2, sz256); diffuse<u16><<<g4, blk, 0, stream>>>(z1, Scb, z2);
        combine_relu<32, 16><<<gridCmb, blk, 0, stream>>>(yA, z1, z2, Wc2, bc2, yB);
        // Layer 3: line, Fin=16 (M=128) -> Fout=32
        ZERO(z1, sz128); diffuse<u16><<<g2, blk, 0, stream>>>(yB, Slb, z1);
        ZERO(z2, sz128); diffuse<u16><<<g2, blk, 0, stream>>>(z1, Slb, z2);
        combine_relu<16, 32><<<gridCmb, blk, 0, stream>>>(yB, z1, z2, Wl1, bl1, yA);
        // Layer 4: line, Fin=32 (M=256) -> Fout=16
        ZERO(z1, sz256); diffuse<u16><<<g4, blk, 0, stream>>>(yA, Slb, z1);
        ZERO(z2, sz256); diffuse<u16><<<g4, blk, 0, stream>>>(z1, Slb, z2);
        combine_relu<32, 16><<<gridCmb, blk, 0, stream>>>(yA, z1, z2, Wl2, bl2, yB);
    } else {
        // Fallback: stage S f32 tiles directly (converted in-kernel).
        ZERO(z1, sz128); diffuse<float><<<g2, blk, 0, stream>>>(x, Sc, z1);
        ZERO(z2, sz128); diffuse<float><<<g2, blk, 0, stream>>>(z1, Sc, z2);
        combine_relu<16, 32><<<gridCmb, blk, 0, stream>>>(x, z1, z2, Wc1, bc1, yA);
        ZERO(z1, sz256); diffuse<float><<<g4, blk, 0, stream>>>(yA, Sc, z1);
        ZERO(z2, sz256); diffuse<float><<<g4, blk, 0, stream>>>(z1, Sc, z2);
        combine_relu<32, 16><<<gridCmb, blk, 0, stream>>>(yA, z1, z2, Wc2, bc2, yB);
        ZERO(z1, sz128); diffuse<float><<<g2, blk, 0, stream>>>(yB, Sl, z1);
        ZERO(z2, sz128); diffuse<float><<<g2, blk, 0, stream>>>(z1, Sl, z2);
        combine_relu<16, 32><<<gridCmb, blk, 0, stream>>>(yB, z1, z2, Wl1, bl1, yA);
        ZERO(z1, sz256); diffuse<float><<<g4, blk, 0, stream>>>(yA, Sl, z1);
        ZERO(z2, sz256); diffuse<float><<<g4, blk, 0, stream>>>(z1, Sl, z2);
        combine_relu<32, 16><<<gridCmb, blk, 0, stream>>>(yA, z1, z2, Wl2, bl2, yB);
    }
    mlp1<<<64, blk, 0, stream>>>(yB, Wm1, bm1, h1);
    mlp2<<<1, 64, 0, stream>>>(h1, Wm2, bm2, out);
#undef ZERO
}

// Round 4
// 576.606 us; speedup vs baseline: 2.2086x; 1.0607x over previous
//
#include <hip/hip_runtime.h>

// SelectionGNN clique+line. I/O: float32 (per reference). Internals: bf16 MFMA
// with fp32 accumulate; intermediates stored f32 (only MFMA inputs rounded).
// B=8, N=4096, E=1, K=3 taps, F=[16,32,16], MLP 65536->64->1.
// R3: (a) 128x128 diffuse tile w/ exact K-partition + XCD swizzle (S staged
// once, S-slice lives in its XCD's L2), (b) split-K mlp1 (512 blocks).

#define NN 4096
#define BB 8

typedef unsigned short u16;
typedef unsigned int   u32;

typedef __attribute__((ext_vector_type(8))) short bf16x8;  // 8 bf16 = 4 VGPRs
typedef __attribute__((ext_vector_type(4))) float f32x4;

__device__ __forceinline__ u16 f2bf(float f) {
    union { float f; u32 i; } c; c.f = f;
    u32 i = c.i;
    u32 r = (i + 0x7FFFu + ((i >> 16) & 1u)) >> 16;  // RTNE
    return (u16)r;
}

// ---------------------------------------------------------------------------
// f32 -> bf16 conversion (for S matrices), grid-stride, float4 -> ushort4.
// ---------------------------------------------------------------------------
__global__ __launch_bounds__(256) void cvt_f32_bf16(const float* __restrict__ in,
                                                    u16* __restrict__ out, int n)
{
    int i = (blockIdx.x * 256 + threadIdx.x) * 4;
    const int stride = gridDim.x * 256 * 4;
    for (; i < n; i += stride) {
        float4 v = *(const float4*)(in + i);
        ushort4 o;
        o.x = f2bf(v.x); o.y = f2bf(v.y); o.z = f2bf(v.z); o.w = f2bf(v.w);
        *(ushort4*)(out + i) = o;
    }
}

// ---------------------------------------------------------------------------
// Split-K diffusion, 128x128 tile: Out[r,n] += sum_{k-slice} Z[r,k]*S[n,k]
// (C = Z*S^T, f32 atomic accumulate; Out pre-zeroed).
// Z: [M,4096] f32. S: [4096,4096] bf16 (f32 fallback). BK=64.
// grid: (32, M/128, KS). blockIdx.x is XCD-swizzled so each XCD owns a
// contiguous 512-row slice of S (4 MB = its L2). K-slice = NN/KS.
// 256 threads = 4 waves in 2x2; wave owns 64x64 via 4x4 mfma_16x16x32_bf16.
// ---------------------------------------------------------------------------
template <typename TB>
__global__ __launch_bounds__(256) void diffuse(const float* __restrict__ Z,
                                               const TB* __restrict__ S,
                                               float* __restrict__ Out)
{
    // +8 pad (144 B row stride): 2-way bank aliasing on ds_read_b128 is free.
    __shared__ u16 As[128][72];
    __shared__ u16 Bs[128][72];

    const int bx    = blockIdx.x;                    // 0..31
    const int ntile = ((bx & 7) << 2) | (bx >> 3);   // XCD swizzle
    const int nBase = ntile * 128;
    const int mBase = blockIdx.y * 128;
    const int tid   = threadIdx.x;

    const int kSlice = NN / (int)gridDim.z;
    const int kStart = (int)blockIdx.z * kSlice;
    const int kEnd   = kStart + kSlice;

    // staging coords
    const int ar = tid >> 4;          // 0..15 (f32: 16 thr x float4 per row)
    const int ac = (tid & 15) * 4;    // 0,4,..,60
    const int br = tid >> 3;          // 0..31 (bf16: 8 thr x 8 elems per row)
    const int bc = (tid & 7) * 8;     // 0,8,..,56

    // compute coords
    const int lane = tid & 63;
    const int wv   = tid >> 6;
    const int wm   = wv >> 1;         // 0..1: which 64-row half
    const int wn   = wv & 1;          // 0..1: which 64-col half
    const int quad = lane >> 4;
    const int l16  = lane & 15;

    f32x4 acc[4][4];
#pragma unroll
    for (int i = 0; i < 4; ++i)
#pragma unroll
        for (int j = 0; j < 4; ++j) acc[i][j] = (f32x4){0.f, 0.f, 0.f, 0.f};

    for (int k0 = kStart; k0 < kEnd; k0 += 64) {
        // A tile: 128 rows x 64 k, f32 -> bf16
#pragma unroll
        for (int p = 0; p < 8; ++p) {
            const int r = ar + p * 16;
            float4 v = *(const float4*)(Z + (size_t)(mBase + r) * NN + k0 + ac);
            ushort4 o;
            o.x = f2bf(v.x); o.y = f2bf(v.y); o.z = f2bf(v.z); o.w = f2bf(v.w);
            *(ushort4*)&As[r][ac] = o;
        }
        // B tile: 128 rows x 64 k
        if constexpr (sizeof(TB) == 2) {
#pragma unroll
            for (int p = 0; p < 4; ++p) {
                const int r = br + p * 32;
                *(uint4*)&Bs[r][bc] =
                    *(const uint4*)((const u16*)S + (size_t)(nBase + r) * NN + k0 + bc);
            }
        } else {
#pragma unroll
            for (int p = 0; p < 8; ++p) {
                const int r = ar + p * 16;
                float4 v = *(const float4*)((const float*)S + (size_t)(nBase + r) * NN + k0 + ac);
                ushort4 o;
                o.x = f2bf(v.x); o.y = f2bf(v.y); o.z = f2bf(v.z); o.w = f2bf(v.w);
                *(ushort4*)&Bs[r][ac] = o;
            }
        }
        __syncthreads();

#pragma unroll
        for (int s = 0; s < 2; ++s) {
            const int kc = s * 32 + quad * 8;
            bf16x8 af[4], bf[4];
#pragma unroll
            for (int mi = 0; mi < 4; ++mi)
                af[mi] = *(const bf16x8*)&As[wm * 64 + mi * 16 + l16][kc];
#pragma unroll
            for (int ni = 0; ni < 4; ++ni)
                bf[ni] = *(const bf16x8*)&Bs[wn * 64 + ni * 16 + l16][kc];
#pragma unroll
            for (int mi = 0; mi < 4; ++mi)
#pragma unroll
                for (int ni = 0; ni < 4; ++ni)
                    acc[mi][ni] = __builtin_amdgcn_mfma_f32_16x16x32_bf16(
                        af[mi], bf[ni], acc[mi][ni], 0, 0, 0);
        }
        __syncthreads();
    }

    // D mapping: col = lane&15, row = quad*4 + reg.  Atomic accumulate.
#pragma unroll
    for (int mi = 0; mi < 4; ++mi)
#pragma unroll
        for (int ni = 0; ni < 4; ++ni) {
            const int row0 = mBase + wm * 64 + mi * 16 + quad * 4;
            const int col  = nBase + wn * 64 + ni * 16 + l16;
#pragma unroll
            for (int i = 0; i < 4; ++i)
                atomicAdd(&Out[(size_t)(row0 + i) * NN + col], acc[mi][ni][i]);
        }
}

// ---------------------------------------------------------------------------
// Tap combine + ReLU (all f32):
// out[b,g,n] = relu( bias[g] + sum_{k<3} sum_{f<FIN} W[g,k,f] * z_k[b,f,n] )
// grid: BB*NN/256, 256 threads, one (b,n) per thread.
// ---------------------------------------------------------------------------
template <int FIN, int FOUT>
__global__ __launch_bounds__(256) void combine_relu(
    const float* __restrict__ z0, const float* __restrict__ z1,
    const float* __restrict__ z2, const float* __restrict__ W,
    const float* __restrict__ bias, float* __restrict__ out)
{
    __shared__ float hs[FOUT * 3 * FIN];
    __shared__ float bs[FOUT];
    for (int i = threadIdx.x; i < FOUT * 3 * FIN; i += 256) hs[i] = W[i];
    if (threadIdx.x < FOUT) bs[threadIdx.x] = bias[threadIdx.x];
    __syncthreads();

    const int nb = NN / 256;                 // 16
    const int b  = blockIdx.x / nb;
    const int n  = (blockIdx.x % nb) * 256 + threadIdx.x;

    float zv[3][FIN];
    const float* zp0 = z0 + (size_t)b * FIN * NN + n;
    const float* zp1 = z1 + (size_t)b * FIN * NN + n;
    const float* zp2 = z2 + (size_t)b * FIN * NN + n;
#pragma unroll
    for (int f = 0; f < FIN; ++f) {
        zv[0][f] = zp0[(size_t)f * NN];
        zv[1][f] = zp1[(size_t)f * NN];
        zv[2][f] = zp2[(size_t)f * NN];
    }

    float* op = out + (size_t)b * FOUT * NN + n;
    for (int g = 0; g < FOUT; ++g) {
        float acc = bs[g];
#pragma unroll
        for (int k = 0; k < 3; ++k)
#pragma unroll
            for (int f = 0; f < FIN; ++f)
                acc = fmaf(hs[(g * 3 + k) * FIN + f], zv[k][f], acc);
        op[(size_t)g * NN] = fmaxf(acc, 0.f);
    }
}

// ---------------------------------------------------------------------------
// MLP layer 1, split-K: partial h1raw[b,j] += sum_{slice} y[b,i]*Wm1[j,i].
// grid: (64 j, 8 slices); 256 threads; slice = 8192 elements.
// h1raw must be pre-zeroed. Bias+ReLU applied in mlp2.
// ---------------------------------------------------------------------------
__global__ __launch_bounds__(256) void mlp1(const float* __restrict__ y,
                                            const float* __restrict__ Wm1,
                                            float* __restrict__ h1raw)
{
    const int j    = blockIdx.x;
    const int base = blockIdx.y * 8192;
    const int D    = 16 * NN;  // 65536

    float acc[BB];
#pragma unroll
    for (int b = 0; b < BB; ++b) acc[b] = 0.f;

    const float* wrow = Wm1 + (size_t)j * D + base;
    for (int idx = threadIdx.x * 4; idx < 8192; idx += 256 * 4) {
        float4 w = *(const float4*)(wrow + idx);
#pragma unroll
        for (int b = 0; b < BB; ++b) {
            float4 yv = *(const float4*)(y + (size_t)b * D + base + idx);
            acc[b] = fmaf(w.x, yv.x, acc[b]);
            acc[b] = fmaf(w.y, yv.y, acc[b]);
            acc[b] = fmaf(w.z, yv.z, acc[b]);
            acc[b] = fmaf(w.w, yv.w, acc[b]);
        }
    }

    __shared__ float red[BB][4];
    const int lane = threadIdx.x & 63;
    const int w    = threadIdx.x >> 6;
#pragma unroll
    for (int b = 0; b < BB; ++b) {
        float v = acc[b];
        for (int off = 32; off > 0; off >>= 1) v += __shfl_down(v, off, 64);
        if (lane == 0) red[b][w] = v;
    }
    __syncthreads();
    if (threadIdx.x < BB) {
        const int b = threadIdx.x;
        atomicAdd(&h1raw[b * 64 + j],
                  red[b][0] + red[b][1] + red[b][2] + red[b][3]);
    }
}

// ---------------------------------------------------------------------------
// MLP layer 2 (+ layer-1 bias/ReLU):
// out[b] = bm2 + sum_j relu(h1raw[b,j]+bm1[j]) * Wm2[j].  1 block, 64 lanes.
// ---------------------------------------------------------------------------
__global__ void mlp2(const float* __restrict__ h1raw,
                     const float* __restrict__ bm1,
                     const float* __restrict__ Wm2,
                     const float* __restrict__ bm2, float* __restrict__ out)
{
    const int lane = threadIdx.x;  // 0..63
    const float w    = Wm2[lane];
    const float b1   = bm1[lane];
    const float bias = bm2[0];
    for (int b = 0; b < BB; ++b) {
        float v = fmaxf(h1raw[b * 64 + lane] + b1, 0.f) * w;
        for (int off = 32; off > 0; off >>= 1) v += __shfl_down(v, off, 64);
        if (lane == 0) out[b] = v + bias;
    }
}

// ---------------------------------------------------------------------------
extern "C" void kernel_launch(void* const* d_in, const int* in_sizes, int n_in,
                              void* d_out, int out_size, void* d_ws, size_t ws_size,
                              hipStream_t stream)
{
    const float* x   = (const float*)d_in[0];   // [8,16,4096]
    const float* Sc  = (const float*)d_in[1];   // [1,4096,4096]
    const float* Sl  = (const float*)d_in[2];   // [1,4096,4096]
    const float* Wc1 = (const float*)d_in[3];
    const float* bc1 = (const float*)d_in[4];
    const float* Wc2 = (const float*)d_in[5];
    const float* bc2 = (const float*)d_in[6];
    const float* Wl1 = (const float*)d_in[7];
    const float* bl1 = (const float*)d_in[8];
    const float* Wl2 = (const float*)d_in[9];
    const float* bl2 = (const float*)d_in[10];
    const float* Wm1 = (const float*)d_in[11];  // [64,65536]
    const float* bm1 = (const float*)d_in[12];
    const float* Wm2 = (const float*)d_in[13];  // [1,64]
    const float* bm2 = (const float*)d_in[14];
    float* out = (float*)d_out;                 // [8,1] f32

    char* ws = (char*)d_ws;
    float* z1 = (float*)(ws);                    // 4 MB ([8,32,4096] f32 max)
    float* z2 = (float*)(ws + (4u << 20));       // 4 MB
    float* yA = (float*)(ws + (8u << 20));       // 4 MB
    float* yB = (float*)(ws + (12u << 20));      // 4 MB
    float* h1 = (float*)(ws + (16u << 20));      // 2 KB
    u16* Scb  = (u16*)(ws + (17u << 20));        // 32 MB
    u16* Slb  = Scb + (size_t)NN * NN;           // 32 MB
    const size_t needed = (17u << 20) + 2 * (size_t)NN * NN * sizeof(u16);
    const bool bigws = ws_size >= needed;

    const dim3 blk(256);
    const dim3 gridCmb(BB * NN / 256);           // 128
    // 128x128 tiles, exact K-partition: 512 blocks both shapes
    const dim3 g2(32, 1, 16);                    // M=128: KS=16, slice 256
    const dim3 g4(32, 2, 8);                     // M=256: KS=8, slice 512
    const dim3 gM(64, 8);                        // mlp1 split

    const size_t sz128 = (size_t)128 * NN * sizeof(float);  // 2 MB
    const size_t sz256 = (size_t)256 * NN * sizeof(float);  // 4 MB

#define ZERO(p, b) hipMemsetAsync((p), 0, (b), stream)

    if (bigws) {
        cvt_f32_bf16<<<1024, blk, 0, stream>>>(Sc, Scb, NN * NN);
        cvt_f32_bf16<<<1024, blk, 0, stream>>>(Sl, Slb, NN * NN);
        // Layer 1: clique, Fin=16 (M=128) -> Fout=32
        ZERO(z1, sz128); diffuse<u16><<<g2, blk, 0, stream>>>(x, Scb, z1);
        ZERO(z2, sz128); diffuse<u16><<<g2, blk, 0, stream>>>(z1, Scb, z2);
        combine_relu<16, 32><<<gridCmb, blk, 0, stream>>>(x, z1, z2, Wc1, bc1, yA);
        // Layer 2: clique, Fin=32 (M=256) -> Fout=16
        ZERO(z1, sz256); diffuse<u16><<<g4, blk, 0, stream>>>(yA, Scb, z1);
        ZERO(z2, sz256); diffuse<u16><<<g4, blk, 0, stream>>>(z1, Scb, z2);
        combine_relu<32, 16><<<gridCmb, blk, 0, stream>>>(yA, z1, z2, Wc2, bc2, yB);
        // Layer 3: line, Fin=16 (M=128) -> Fout=32
        ZERO(z1, sz128); diffuse<u16><<<g2, blk, 0, stream>>>(yB, Slb, z1);
        ZERO(z2, sz128); diffuse<u16><<<g2, blk, 0, stream>>>(z1, Slb, z2);
        combine_relu<16, 32><<<gridCmb, blk, 0, stream>>>(yB, z1, z2, Wl1, bl1, yA);
        // Layer 4: line, Fin=32 (M=256) -> Fout=16
        ZERO(z1, sz256); diffuse<u16><<<g4, blk, 0, stream>>>(yA, Slb, z1);
        ZERO(z2, sz256); diffuse<u16><<<g4, blk, 0, stream>>>(z1, Slb, z2);
        combine_relu<32, 16><<<gridCmb, blk, 0, stream>>>(yA, z1, z2, Wl2, bl2, yB);
    } else {
        // Fallback: stage S f32 tiles directly (converted in-kernel).
        ZERO(z1, sz128); diffuse<float><<<g2, blk, 0, stream>>>(x, Sc, z1);
        ZERO(z2, sz128); diffuse<float><<<g2, blk, 0, stream>>>(z1, Sc, z2);
        combine_relu<16, 32><<<gridCmb, blk, 0, stream>>>(x, z1, z2, Wc1, bc1, yA);
        ZERO(z1, sz256); diffuse<float><<<g4, blk, 0, stream>>>(yA, Sc, z1);
        ZERO(z2, sz256); diffuse<float><<<g4, blk, 0, stream>>>(z1, Sc, z2);
        combine_relu<32, 16><<<gridCmb, blk, 0, stream>>>(yA, z1, z2, Wc2, bc2, yB);
        ZERO(z1, sz128); diffuse<float><<<g2, blk, 0, stream>>>(yB, Sl, z1);
        ZERO(z2, sz128); diffuse<float><<<g2, blk, 0, stream>>>(z1, Sl, z2);
        combine_relu<16, 32><<<gridCmb, blk, 0, stream>>>(yB, z1, z2, Wl1, bl1, yA);
        ZERO(z1, sz256); diffuse<float><<<g4, blk, 0, stream>>>(yA, Sl, z1);
        ZERO(z2, sz256); diffuse<float><<<g4, blk, 0, stream>>>(z1, Sl, z2);
        combine_relu<32, 16><<<gridCmb, blk, 0, stream>>>(yA, z1, z2, Wl2, bl2, yB);
    }
    ZERO(h1, 64 * BB * sizeof(float));
    mlp1<<<gM, blk, 0, stream>>>(yB, Wm1, h1);
    mlp2<<<1, 64, 0, stream>>>(h1, bm1, Wm2, bm2, out);
#undef ZERO
}